// Round 12
// baseline (246.710 us; speedup 1.0000x reference)
//
#include <hip/hip_runtime.h>

// ---------------------------------------------------------------------------
// CorefPairScorer: B=4, T=4096, D=768, N=256, HID=200 (padded to 224)
// h1(i,j) = relu(A[i] + Bv[j] + (emb_i*emb_j)@W1bot + b1)
// h2 = relu(h1@W2 + b2); s = h2@W3 + b3; masked softmax rows.
// R14->R17: reg ping-pong only PARTIALLY overlaps (148->119, not ->99);
//   residual stall = compiler-placed register waitcnts on the 56-VGPR weight
//   buffers. R18: weight stream moved to wave-PRIVATE LDS slices via
//   global_load_lds DMA (3 slices/wave, depth-2 lookahead) with hand-counted
//   s_waitcnt vmcnt(N) (steady 17, edges 12/10, never 0, no barriers in
//   K-loop; VM ops retire in order per m135). Frees 56 VGPRs; ds_read_b128
//   linear = conflict-free. LDS 29->72KB (2 blk/CU). emb stays in reg
//   ping-pong. Phase2/epilogue/phase3 unchanged from R17.
// ---------------------------------------------------------------------------

#define NB 4
#define NN 256
#define DD 768
#define TT 4096
#define HP 224
#define NTILES 14
#define KT1 24
#define KT2 7
#define TRI 136
#define ABS 448          // AB row stride (fp16): [A(224) | B(224)]
#define MTS 3584         // shorts per packed Mtile (16 rows x 224)
#define WSH 3584         // shorts per weight K-slice (7 subtiles x 512)

typedef _Float16 f16x8 __attribute__((ext_vector_type(8)));
typedef _Float16 f16x2 __attribute__((ext_vector_type(2)));
typedef __attribute__((ext_vector_type(4))) float f32x4;

union FragU { uint4 u; f16x8 h; };
union H2U { unsigned int u; f16x2 h; };

__device__ __forceinline__ unsigned int h2mul(unsigned int a, unsigned int b) {
    H2U x, y, r; x.u = a; y.u = b; r.h = x.h * y.h;   // v_pk_mul_f16
    return r.u;
}
__device__ __forceinline__ float hlo(unsigned int v) { H2U x; x.u = v; return (float)x.h[0]; }
__device__ __forceinline__ float hhi(unsigned int v) { H2U x; x.u = v; return (float)x.h[1]; }
__device__ __forceinline__ unsigned short f2h(float f) {
    _Float16 h = (_Float16)f;
    union { _Float16 h; unsigned short u; } r; r.h = h; return r.u;
}
__device__ __forceinline__ float h2f(unsigned short u) {
    union { unsigned short u; _Float16 h; } r; r.u = u; return (float)r.h;
}
__device__ __forceinline__ unsigned int packh(float lo, float hi) {  // RNE pair
    return ((unsigned int)f2h(hi) << 16) | (unsigned int)f2h(lo);
}
// async global->LDS DMA, 16 B per lane (dest uniform-base + lane*16).
__device__ __forceinline__ void gload_lds16(const unsigned short* g, unsigned short* l) {
    __builtin_amdgcn_global_load_lds(
        (const __attribute__((address_space(1))) unsigned int*)g,
        (__attribute__((address_space(3))) unsigned int*)l, 16, 0, 0);
}

// ---------------------------------------------------------------------------
// K0 (merged, vectorized): weight swizzle blocks 0..276 (8 elems/thread,
// uint4 stores) + gather/cast blocks 277..532 (4 rows/block, packed stores).
//   frag layout: buf[((kt*NT+nt)*64+lane)*8+j] = W[kt*32+(lane>>4)*8+j][nt*16+(lane&15)]
// ---------------------------------------------------------------------------
__global__ void prep_all(const float* __restrict__ W1, const float* __restrict__ W2,
                         const float* __restrict__ ee, const int* __restrict__ eidx,
                         unsigned short* __restrict__ w1n,
                         unsigned short* __restrict__ w1s,
                         unsigned short* __restrict__ w2s,
                         unsigned short* __restrict__ emb) {
    const int N1n8 = 24 * 28 * 64;   // 43008  (uint4-granular counts)
    const int N1s8 = 24 * 14 * 64;   // 21504
    const int N28  = 7 * 14 * 64;    // 6272
    int bx = blockIdx.x;
    if (bx >= 277) {                  // gather + fp32->fp16, 4 rows/block
        int tid = threadIdx.x;
        int m = (bx - 277) * 4 + (tid >> 6);   // global row 0..1023
        int lane = tid & 63;
        int b = m >> 8, n = m & 255;
        int t = eidx[b * NN + n];
        const float* src = ee + ((size_t)b * TT + t) * DD;
        uint4* dst = (uint4*)(emb + ((size_t)b * NN + n) * DD);
        for (int chunk = lane; chunk < 96; chunk += 64) {
            const float4* s4 = (const float4*)(src + chunk * 8);
            float4 lo4 = s4[0], hi4 = s4[1];
            uint4 o;
            o.x = packh(lo4.x, lo4.y); o.y = packh(lo4.z, lo4.w);
            o.z = packh(hi4.x, hi4.y); o.w = packh(hi4.z, hi4.w);
            dst[chunk] = o;
        }
        return;
    }
    int idx8 = bx * 256 + threadIdx.x;
    if (idx8 < N1n8) {
        int lane = idx8 & 63, f = idx8 >> 6;
        int nt = f % 28, kt = f / 28;
        int k0 = kt * 32 + ((lane >> 4) << 3);     // base k, +j below
        int n = nt * 16 + (lane & 15);             // 0..447
        unsigned int o[4];
#pragma unroll
        for (int jp = 0; jp < 4; ++jp) {
            float v0, v1;
            int ka = k0 + 2 * jp, kb = ka + 1;
            if (n < HP) {
                v0 = (n < 200) ? W1[(size_t)ka * 200 + n] : 0.f;
                v1 = (n < 200) ? W1[(size_t)kb * 200 + n] : 0.f;
            } else {
                int c2 = n - HP;
                v0 = (c2 < 200) ? W1[(size_t)(768 + ka) * 200 + c2] : 0.f;
                v1 = (c2 < 200) ? W1[(size_t)(768 + kb) * 200 + c2] : 0.f;
            }
            o[jp] = packh(v0, v1);
        }
        *(uint4*)&w1n[(size_t)idx8 * 8] = make_uint4(o[0], o[1], o[2], o[3]);
    } else if (idx8 < N1n8 + N1s8) {
        int i2 = idx8 - N1n8;
        int lane = i2 & 63, f = i2 >> 6;
        int nt = f % NTILES, kt = f / NTILES;
        int k0 = kt * 32 + ((lane >> 4) << 3);
        int n = nt * 16 + (lane & 15);
        unsigned int o[4];
#pragma unroll
        for (int jp = 0; jp < 4; ++jp) {
            int ka = k0 + 2 * jp, kb = ka + 1;
            float v0 = (n < 200) ? W1[(size_t)(1536 + ka) * 200 + n] : 0.f;
            float v1 = (n < 200) ? W1[(size_t)(1536 + kb) * 200 + n] : 0.f;
            o[jp] = packh(v0, v1);
        }
        *(uint4*)&w1s[(size_t)i2 * 8] = make_uint4(o[0], o[1], o[2], o[3]);
    } else if (idx8 < N1n8 + N1s8 + N28) {
        int i2 = idx8 - N1n8 - N1s8;
        int lane = i2 & 63, f = i2 >> 6;
        int nt = f % NTILES, kt = f / NTILES;
        int k0 = kt * 32 + ((lane >> 4) << 3);
        int n = nt * 16 + (lane & 15);
        unsigned int o[4];
#pragma unroll
        for (int jp = 0; jp < 4; ++jp) {
            int ka = k0 + 2 * jp, kb = ka + 1;
            float v0 = (ka < 200 && n < 200) ? W2[(size_t)ka * 200 + n] : 0.f;
            float v1 = (kb < 200 && n < 200) ? W2[(size_t)kb * 200 + n] : 0.f;
            o[jp] = packh(v0, v1);
        }
        *(uint4*)&w2s[(size_t)i2 * 8] = make_uint4(o[0], o[1], o[2], o[3]);
    }
}

// ---------------------------------------------------------------------------
// K2: AB = emb(1024x768) @ [W1top|W1mid](768x448), fp16 MFMA, fp16 out.
//   256 one-wave blocks; register ping-pong prefetch.
// ---------------------------------------------------------------------------
__global__ __launch_bounds__(64)
void node_mfma(const unsigned short* __restrict__ emb,
               const unsigned short* __restrict__ w1n,
               unsigned short* __restrict__ AB) {
    int lane = threadIdx.x & 63;
    int q = lane >> 4, c = lane & 15;
    int mt = blockIdx.x >> 2;         // 0..63
    int ng = blockIdx.x & 3;          // 0..3
    int m0 = mt * 16;
    const uint4* ga = (const uint4*)emb + (size_t)(m0 + c) * 96;
    const uint4* gb = (const uint4*)w1n;

    f32x4 acc[7];
#pragma unroll
    for (int n = 0; n < 7; ++n) acc[n] = (f32x4){0.f, 0.f, 0.f, 0.f};

    uint4 aA, aB, bA[7], bB[7];
    aA = ga[q];
#pragma unroll
    for (int n = 0; n < 7; ++n) bA[n] = gb[((0 * 28 + ng * 7 + n) << 6) + lane];

#pragma unroll 1
    for (int kt = 0; kt < KT1; kt += 2) {
        aB = ga[(kt + 1) * 4 + q];
#pragma unroll
        for (int n = 0; n < 7; ++n) bB[n] = gb[(((kt + 1) * 28 + ng * 7 + n) << 6) + lane];
        {
            FragU a; a.u = aA;
#pragma unroll
            for (int n = 0; n < 7; ++n) {
                FragU bb; bb.u = bA[n];
                acc[n] = __builtin_amdgcn_mfma_f32_16x16x32_f16(a.h, bb.h, acc[n], 0, 0, 0);
            }
        }
        if (kt + 2 < KT1) {
            aA = ga[(kt + 2) * 4 + q];
#pragma unroll
            for (int n = 0; n < 7; ++n) bA[n] = gb[(((kt + 2) * 28 + ng * 7 + n) << 6) + lane];
        }
        {
            FragU a; a.u = aB;
#pragma unroll
            for (int n = 0; n < 7; ++n) {
                FragU bb; bb.u = bB[n];
                acc[n] = __builtin_amdgcn_mfma_f32_16x16x32_f16(a.h, bb.h, acc[n], 0, 0, 0);
            }
        }
    }
#pragma unroll
    for (int n = 0; n < 7; ++n) {
        int col = (ng * 7 + n) * 16 + c;
#pragma unroll
        for (int rr = 0; rr < 4; ++rr)
            AB[(size_t)(m0 + q * 4 + rr) * ABS + col] = f2h(acc[n][rr]);
    }
}

// ---------------------------------------------------------------------------
// K3: pair MLP. Block = 128 threads = 2 waves (the nh pair) for one
//   (tile, 4-i-row group rp). acc[4][7], 28 MFMA per weight slice.
//   R18: phase1 weights DMA-staged into 3 wave-private LDS slices with
//   counted vmcnt (17/12/10), no barriers in the K-loop; emb reg ping-pong.
// ---------------------------------------------------------------------------
__global__ __launch_bounds__(128, 2)
void pair_wave(
    const unsigned short* __restrict__ emb,
    const unsigned short* __restrict__ w1s,
    const unsigned short* __restrict__ w2s,
    const unsigned short* __restrict__ AB,
    const float* __restrict__ b1, const float* __restrict__ b2,
    const float* __restrict__ W3, const float* __restrict__ b3,
    float* __restrict__ S) {
    int bid = blockIdx.x;
    int rp = bid / 544;               // 0..3 : 4-row group within tile
    int g = bid % 544;                // tile id; mates 544 apart (544%8==0)
    int b = g / TRI;
    int r = g % TRI;
    int ti = (int)((sqrtf(8.f * (float)r + 1.f) - 1.f) * 0.5f);
    while ((ti + 1) * (ti + 2) / 2 <= r) ++ti;
    while (ti * (ti + 1) / 2 > r) --ti;
    int tj = r - ti * (ti + 1) / 2;
    int i0 = ti << 4, j0 = tj << 4;

    int tid = threadIdx.x;
    int lane = tid & 63;
    int nh = tid >> 6;                // 0..1 (ntile half)
    int q = lane >> 4, c = lane & 15;
    int iA = i0 + rp * 4;             // rows iA..iA+3

    __shared__ __align__(16) unsigned short smH[4 * MTS];     // 28672 B (4 slots)
    __shared__ __align__(16) unsigned short smW[2 * 3 * WSH]; // 43008 B (2 waves x 3 slices)
    __shared__ float sred[2][64];                             //   512 B
    unsigned short* myW = &smW[nh * 3 * WSH];                 // wave-private

    const uint4* w2f = (const uint4*)w2s;
    const uint4* gI[4];
#pragma unroll
    for (int t = 0; t < 4; ++t)
        gI[t] = (const uint4*)(emb + ((size_t)b * NN + iA + t) * DD);
    const uint4* gJc = (const uint4*)(emb + ((size_t)b * NN + j0 + c) * DD);

    // DMA one weight K-slice (7 subtiles x 1024B, linear) into slice bsel.
    auto stageW = [&](int kt, int bsel) {
#pragma unroll
        for (int n = 0; n < 7; ++n)
            gload_lds16(w1s + ((size_t)((kt * NTILES + nh * 7 + n) * 64) + lane) * 8,
                        myW + bsel * WSH + n * 512 + lane * 8);
    };

    // ---- phase 1: acc[4][7] over K=768, DMA-pipelined weights ----
    f32x4 acc[4][7];
#pragma unroll
    for (int t = 0; t < 4; ++t)
#pragma unroll
        for (int n = 0; n < 7; ++n)
            acc[t][n] = (f32x4){0.f, 0.f, 0.f, 0.f};

    {
        uint4 ejA, ejB, eA[4], eB[4];
        // prologue: D0->slice0 (7 ops), D1->slice1 (7 ops), E0 (5 ops)
        stageW(0, 0);
        stageW(1, 1);
        ejA = gJc[q];
#pragma unroll
        for (int t = 0; t < 4; ++t) eA[t] = gI[t][q];

        int b0 = 0;  // slice holding kt
#pragma unroll 1
        for (int kt = 0; kt < KT1; kt += 2) {
            int b1 = b0 + 1; if (b1 > 2) b1 -= 3;
            int b2 = b1 + 1; if (b2 > 2) b2 -= 3;
            // s1: wait for D(kt), read bfrA (counts: after D(kt) come
            //     E(kt-1)5 + D(kt+1)7 + E(kt)5 = 17; kt=0: D1(7)+E0(5)=12)
            if (kt == 0) asm volatile("s_waitcnt vmcnt(12)" ::: "memory");
            else         asm volatile("s_waitcnt vmcnt(17)" ::: "memory");
            uint4 bfrA[7];
            {
                const uint4* wf = (const uint4*)(myW + b0 * WSH);
#pragma unroll
                for (int n = 0; n < 7; ++n) bfrA[n] = wf[n * 64 + lane];
            }
            // s2: stage D(kt+2) -> b2
            if (kt + 2 < KT1) stageW(kt + 2, b2);
            // s3: emb E(kt+1)
            ejB = gJc[(kt + 1) * 4 + q];
#pragma unroll
            for (int t = 0; t < 4; ++t) eB[t] = gI[t][(kt + 1) * 4 + q];
            // s4: MFMA kt
            __builtin_amdgcn_s_setprio(1);
#pragma unroll
            for (int t = 0; t < 4; ++t) {
                FragU a;
                a.u.x = h2mul(eA[t].x, ejA.x); a.u.y = h2mul(eA[t].y, ejA.y);
                a.u.z = h2mul(eA[t].z, ejA.z); a.u.w = h2mul(eA[t].w, ejA.w);
#pragma unroll
                for (int n = 0; n < 7; ++n) {
                    FragU bb; bb.u = bfrA[n];
                    acc[t][n] = __builtin_amdgcn_mfma_f32_16x16x32_f16(a.h, bb.h, acc[t][n], 0, 0, 0);
                }
            }
            __builtin_amdgcn_s_setprio(0);
            // s5: wait for D(kt+1), read bfrB (after D(kt+1): E(kt)5 +
            //     D(kt+2)7 + E(kt+1)5 = 17; kt=22: E22(5)+E23(5) = 10)
            if (kt == 22) asm volatile("s_waitcnt vmcnt(10)" ::: "memory");
            else          asm volatile("s_waitcnt vmcnt(17)" ::: "memory");
            uint4 bfrB[7];
            {
                const uint4* wf = (const uint4*)(myW + b1 * WSH);
#pragma unroll
                for (int n = 0; n < 7; ++n) bfrB[n] = wf[n * 64 + lane];
            }
            // s6: stage D(kt+3) -> b0 (slice read at s1; reads drained
            //     before s4's MFMAs issued -> safe WAR)
            asm volatile("" ::: "memory");
            if (kt + 3 < KT1) stageW(kt + 3, b0);
            // s7: emb E(kt+2)
            if (kt + 2 < KT1) {
                ejA = gJc[(kt + 2) * 4 + q];
#pragma unroll
                for (int t = 0; t < 4; ++t) eA[t] = gI[t][(kt + 2) * 4 + q];
            }
            // s8: MFMA kt+1
            __builtin_amdgcn_s_setprio(1);
#pragma unroll
            for (int t = 0; t < 4; ++t) {
                FragU a;
                a.u.x = h2mul(eB[t].x, ejB.x); a.u.y = h2mul(eB[t].y, ejB.y);
                a.u.z = h2mul(eB[t].z, ejB.z); a.u.w = h2mul(eB[t].w, ejB.w);
#pragma unroll
                for (int n = 0; n < 7; ++n) {
                    FragU bb; bb.u = bfrB[n];
                    acc[t][n] = __builtin_amdgcn_mfma_f32_16x16x32_f16(a.h, bb.h, acc[t][n], 0, 0, 0);
                }
            }
            __builtin_amdgcn_s_setprio(0);
            b0 = b2;   // next kt's slice = (kt+2)%3
        }
    }

    // ---- epilogue: h1 = relu(acc + A[i] + Bv[j] + b1) -> smH (nh half) ----
    {
        unsigned int bvp[7][2];
#pragma unroll
        for (int n = 0; n < 7; ++n) {
            int h = ((nh * 7 + n) << 4) + c;
#pragma unroll
            for (int p = 0; p < 2; ++p) {
                unsigned int lo = AB[((size_t)b * NN + j0 + q * 4 + 2 * p) * ABS + HP + h];
                unsigned int hi = AB[((size_t)b * NN + j0 + q * 4 + 2 * p + 1) * ABS + HP + h];
                bvp[n][p] = (hi << 16) | lo;
            }
        }
#pragma unroll
        for (int t = 0; t < 4; ++t) {
            unsigned short* slot = &smH[t * MTS];
#pragma unroll
            for (int n = 0; n < 7; ++n) {
                int h = ((nh * 7 + n) << 4) + c;
                float b1v = (h < 200) ? b1[h] : 0.f;
                float af = h2f(AB[((size_t)b * NN + iA + t) * ABS + h]) + b1v;
                int kk2 = h >> 5, q2 = (h >> 3) & 3, j2 = h & 7;
                int fa = ((kk2 * 4 + q2) << 7) + j2;        // + jj*8 below
#pragma unroll
                for (int rr = 0; rr < 4; ++rr) {
                    float bvf = (rr & 1) ? hhi(bvp[n][rr >> 1]) : hlo(bvp[n][rr >> 1]);
                    slot[fa + ((q * 4 + rr) << 3)] =
                        f2h(fmaxf(acc[t][n][rr] + af + bvf, 0.f));
                }
            }
        }
    }
    __syncthreads();   // B1: both h-halves of all 4 slots in smH

    // ---- phase 2: acc2[4][7] over K=224, ping-pong weight prefetch ----
    f32x4 acc2[4][7];
#pragma unroll
    for (int t = 0; t < 4; ++t)
#pragma unroll
        for (int n = 0; n < 7; ++n)
            acc2[t][n] = (f32x4){0.f, 0.f, 0.f, 0.f};

    {
        uint4 bfrA[7], bfrB[7];
#pragma unroll
        for (int n = 0; n < 7; ++n) bfrA[n] = w2f[(nh * 7 + n) * 64 + lane];

#pragma unroll 1
        for (int kk = 0; kk < 6; kk += 2) {
#pragma unroll
            for (int n = 0; n < 7; ++n)
                bfrB[n] = w2f[((kk + 1) * NTILES + nh * 7 + n) * 64 + lane];
            __builtin_amdgcn_s_setprio(1);
#pragma unroll
            for (int t = 0; t < 4; ++t) {
                FragU a2;
                a2.u = *(const uint4*)(&smH[t * MTS + (((kk * 4 + q) * 16 + c) << 3)]);
#pragma unroll
                for (int n = 0; n < 7; ++n) {
                    FragU bb; bb.u = bfrA[n];
                    acc2[t][n] = __builtin_amdgcn_mfma_f32_16x16x32_f16(a2.h, bb.h, acc2[t][n], 0, 0, 0);
                }
            }
            __builtin_amdgcn_s_setprio(0);
#pragma unroll
            for (int n = 0; n < 7; ++n)
                bfrA[n] = w2f[((kk + 2) * NTILES + nh * 7 + n) * 64 + lane];
            __builtin_amdgcn_s_setprio(1);
#pragma unroll
            for (int t = 0; t < 4; ++t) {
                FragU a2;
                a2.u = *(const uint4*)(&smH[t * MTS + ((((kk + 1) * 4 + q) * 16 + c) << 3)]);
#pragma unroll
                for (int n = 0; n < 7; ++n) {
                    FragU bb; bb.u = bfrB[n];
                    acc2[t][n] = __builtin_amdgcn_mfma_f32_16x16x32_f16(a2.h, bb.h, acc2[t][n], 0, 0, 0);
                }
            }
            __builtin_amdgcn_s_setprio(0);
        }
        // tail kk=6 (already in bfrA)
        __builtin_amdgcn_s_setprio(1);
#pragma unroll
        for (int t = 0; t < 4; ++t) {
            FragU a2;
            a2.u = *(const uint4*)(&smH[t * MTS + (((6 * 4 + q) * 16 + c) << 3)]);
#pragma unroll
            for (int n = 0; n < 7; ++n) {
                FragU bb; bb.u = bfrA[n];
                acc2[t][n] = __builtin_amdgcn_mfma_f32_16x16x32_f16(a2.h, bb.h, acc2[t][n], 0, 0, 0);
            }
        }
        __builtin_amdgcn_s_setprio(0);
    }

    // ---- phase 3: partial dot relu(h2+b2).W3 over nh half -> sred ----
    {
        float b2v[7], w3v[7];
#pragma unroll
        for (int n = 0; n < 7; ++n) {
            int h = ((nh * 7 + n) << 4) + c;
            b2v[n] = (h < 200) ? b2[h] : 0.f;
            w3v[n] = (h < 200) ? W3[h] : 0.f;
        }
#pragma unroll
        for (int t = 0; t < 4; ++t) {
#pragma unroll
            for (int rr = 0; rr < 4; ++rr) {
                float part = 0.f;
#pragma unroll
                for (int n = 0; n < 7; ++n) {
                    float hv = fmaxf(acc2[t][n][rr] + b2v[n], 0.f);
                    part += hv * w3v[n];
                }
                part += __shfl_xor(part, 1);
                part += __shfl_xor(part, 2);
                part += __shfl_xor(part, 4);
                part += __shfl_xor(part, 8);
                if (c == 0)
                    sred[nh][t * 16 + q * 4 + rr] = part;
            }
        }
    }
    __syncthreads();   // B2: both partials in sred

    if (tid < 64) {
        int t = tid >> 4, jj = tid & 15;
        float s = sred[0][tid] + sred[1][tid] + b3[0];
        S[((size_t)b * NN + iA + t) * NN + j0 + jj] = s;
    }
}

// ---------------------------------------------------------------------------
// K4: masked softmax per row; diag logit = 0; invalid -> -1000
// ---------------------------------------------------------------------------
__global__ __launch_bounds__(256) void softmax_rows(const float* __restrict__ S,
                                                    float* __restrict__ out) {
    int b = blockIdx.x >> 8, i = blockIdx.x & 255;
    int j = threadIdx.x;
    int lane = j & 63, w = j >> 6;
    __shared__ float red[16];
    float x = (j < i) ? S[((size_t)b * NN + i) * NN + j] : ((j == i) ? 0.f : -1e30f);
    float m = x;
#pragma unroll
    for (int off = 32; off; off >>= 1) m = fmaxf(m, __shfl_xor(m, off));
    if (lane == 0) red[w] = m;
    __syncthreads();
    float mx = fmaxf(fmaxf(red[0], red[1]), fmaxf(red[2], red[3]));
    float e = (j <= i) ? __expf(x - mx) : 0.f;
    float s = e;
#pragma unroll
    for (int off = 32; off; off >>= 1) s += __shfl_xor(s, off);
    if (lane == 0) red[8 + w] = s;
    __syncthreads();
    float sum = red[8] + red[9] + red[10] + red[11];
    out[((size_t)b * NN + i) * NN + j] = (j <= i) ? (e / sum) : -1000.0f;
}

// ---------------------------------------------------------------------------
extern "C" void kernel_launch(void* const* d_in, const int* in_sizes, int n_in,
                              void* d_out, int out_size, void* d_ws, size_t ws_size,
                              hipStream_t stream) {
    const float* ee  = (const float*)d_in[0];
    const int*   eidx = (const int*)d_in[1];
    const float* W1  = (const float*)d_in[2];
    const float* b1  = (const float*)d_in[3];
    const float* W2  = (const float*)d_in[4];
    const float* b2  = (const float*)d_in[5];
    const float* W3  = (const float*)d_in[6];
    const float* b3  = (const float*)d_in[7];
    float* out = (float*)d_out;

    char* p = (char*)d_ws;
    unsigned short* emb = (unsigned short*)p; p += (size_t)NB * NN * DD * 2;       // 1.5 MB
    unsigned short* w1n = (unsigned short*)p; p += (size_t)24 * 28 * 512 * 2;      // 672 KB
    unsigned short* w1s = (unsigned short*)p; p += (size_t)24 * 14 * 512 * 2;      // 336 KB
    unsigned short* w2s = (unsigned short*)p; p += (size_t)7 * 14 * 512 * 2;       // 98 KB
    unsigned short* AB  = (unsigned short*)p; p += (size_t)NB * NN * ABS * 2;      // 896 KB
    float* S  = (float*)p; p += (size_t)NB * NN * NN * 4;                           // 1 MB

    prep_all<<<533, 256, 0, stream>>>(W1, W2, ee, eidx, w1n, w1s, w2s, emb);
    node_mfma<<<256, 64, 0, stream>>>(emb, w1n, AB);
    pair_wave<<<2176, 128, 0, stream>>>(emb, w1s, w2s, AB, b1, b2, W3, b3, S);
    softmax_rows<<<NB * NN, 256, 0, stream>>>(S, out);
}

// Round 13
// 234.676 us; speedup vs baseline: 1.0513x; 1.0513x over previous
//
#include <hip/hip_runtime.h>

// ---------------------------------------------------------------------------
// CorefPairScorer: B=4, T=4096, D=768, N=256, HID=200 (padded to 224)
// h1(i,j) = relu(A[i] + Bv[j] + (emb_i*emb_j)@W1bot + b1)
// h2 = relu(h1@W2 + b2); s = h2@W3 + b3; masked softmax rows.
// R18 (wave-private LDS DMA weights): REGRESSED 107->148 (VGPR stayed 176,
//   LDS 72KB halved residency, extra LDS round-trip). Falsifier fired:
//   pair_wave structure plateaus at ~107us. R15/R17 geometry is optimal.
// R19: revert to R17 pair_wave; kill the softmax kernel: fuse masked softmax
//   into pair_wave tail. Row i has (i>>4)+1 writer blocks; agent-scope
//   S stores + ACQ_REL agent fetch_add on per-row counters; LAST writer
//   softmaxes the row (agent loads; per-XCD L2 non-coherent, G16). No
//   spinning -> no deadlock. Counters in d_ws, re-zeroed per replay via
//   captured hipMemsetAsync. Saves 4th kernel + launch gap; softmax overlaps
//   with remaining pair blocks.
// ---------------------------------------------------------------------------

#define NB 4
#define NN 256
#define DD 768
#define TT 4096
#define HP 224
#define NTILES 14
#define KT1 24
#define KT2 7
#define TRI 136
#define ABS 448          // AB row stride (fp16): [A(224) | B(224)]
#define MTS 3584         // shorts per packed Mtile (16 rows x 224)

typedef _Float16 f16x8 __attribute__((ext_vector_type(8)));
typedef _Float16 f16x2 __attribute__((ext_vector_type(2)));
typedef __attribute__((ext_vector_type(4))) float f32x4;

union FragU { uint4 u; f16x8 h; };
union H2U { unsigned int u; f16x2 h; };

__device__ __forceinline__ unsigned int h2mul(unsigned int a, unsigned int b) {
    H2U x, y, r; x.u = a; y.u = b; r.h = x.h * y.h;   // v_pk_mul_f16
    return r.u;
}
__device__ __forceinline__ float hlo(unsigned int v) { H2U x; x.u = v; return (float)x.h[0]; }
__device__ __forceinline__ float hhi(unsigned int v) { H2U x; x.u = v; return (float)x.h[1]; }
__device__ __forceinline__ unsigned short f2h(float f) {
    _Float16 h = (_Float16)f;
    union { _Float16 h; unsigned short u; } r; r.h = h; return r.u;
}
__device__ __forceinline__ float h2f(unsigned short u) {
    union { unsigned short u; _Float16 h; } r; r.u = u; return (float)r.h;
}
__device__ __forceinline__ unsigned int packh(float lo, float hi) {  // RNE pair
    return ((unsigned int)f2h(hi) << 16) | (unsigned int)f2h(lo);
}

// ---------------------------------------------------------------------------
// K0 (merged, vectorized): weight swizzle blocks 0..276 (8 elems/thread,
// uint4 stores) + gather/cast blocks 277..532 (4 rows/block, packed stores).
//   frag layout: buf[((kt*NT+nt)*64+lane)*8+j] = W[kt*32+(lane>>4)*8+j][nt*16+(lane&15)]
// ---------------------------------------------------------------------------
__global__ void prep_all(const float* __restrict__ W1, const float* __restrict__ W2,
                         const float* __restrict__ ee, const int* __restrict__ eidx,
                         unsigned short* __restrict__ w1n,
                         unsigned short* __restrict__ w1s,
                         unsigned short* __restrict__ w2s,
                         unsigned short* __restrict__ emb) {
    const int N1n8 = 24 * 28 * 64;   // 43008  (uint4-granular counts)
    const int N1s8 = 24 * 14 * 64;   // 21504
    const int N28  = 7 * 14 * 64;    // 6272
    int bx = blockIdx.x;
    if (bx >= 277) {                  // gather + fp32->fp16, 4 rows/block
        int tid = threadIdx.x;
        int m = (bx - 277) * 4 + (tid >> 6);   // global row 0..1023
        int lane = tid & 63;
        int b = m >> 8, n = m & 255;
        int t = eidx[b * NN + n];
        const float* src = ee + ((size_t)b * TT + t) * DD;
        uint4* dst = (uint4*)(emb + ((size_t)b * NN + n) * DD);
        for (int chunk = lane; chunk < 96; chunk += 64) {
            const float4* s4 = (const float4*)(src + chunk * 8);
            float4 lo4 = s4[0], hi4 = s4[1];
            uint4 o;
            o.x = packh(lo4.x, lo4.y); o.y = packh(lo4.z, lo4.w);
            o.z = packh(hi4.x, hi4.y); o.w = packh(hi4.z, hi4.w);
            dst[chunk] = o;
        }
        return;
    }
    int idx8 = bx * 256 + threadIdx.x;
    if (idx8 < N1n8) {
        int lane = idx8 & 63, f = idx8 >> 6;
        int nt = f % 28, kt = f / 28;
        int k0 = kt * 32 + ((lane >> 4) << 3);     // base k, +j below
        int n = nt * 16 + (lane & 15);             // 0..447
        unsigned int o[4];
#pragma unroll
        for (int jp = 0; jp < 4; ++jp) {
            float v0, v1;
            int ka = k0 + 2 * jp, kb = ka + 1;
            if (n < HP) {
                v0 = (n < 200) ? W1[(size_t)ka * 200 + n] : 0.f;
                v1 = (n < 200) ? W1[(size_t)kb * 200 + n] : 0.f;
            } else {
                int c2 = n - HP;
                v0 = (c2 < 200) ? W1[(size_t)(768 + ka) * 200 + c2] : 0.f;
                v1 = (c2 < 200) ? W1[(size_t)(768 + kb) * 200 + c2] : 0.f;
            }
            o[jp] = packh(v0, v1);
        }
        *(uint4*)&w1n[(size_t)idx8 * 8] = make_uint4(o[0], o[1], o[2], o[3]);
    } else if (idx8 < N1n8 + N1s8) {
        int i2 = idx8 - N1n8;
        int lane = i2 & 63, f = i2 >> 6;
        int nt = f % NTILES, kt = f / NTILES;
        int k0 = kt * 32 + ((lane >> 4) << 3);
        int n = nt * 16 + (lane & 15);
        unsigned int o[4];
#pragma unroll
        for (int jp = 0; jp < 4; ++jp) {
            int ka = k0 + 2 * jp, kb = ka + 1;
            float v0 = (n < 200) ? W1[(size_t)(1536 + ka) * 200 + n] : 0.f;
            float v1 = (n < 200) ? W1[(size_t)(1536 + kb) * 200 + n] : 0.f;
            o[jp] = packh(v0, v1);
        }
        *(uint4*)&w1s[(size_t)i2 * 8] = make_uint4(o[0], o[1], o[2], o[3]);
    } else if (idx8 < N1n8 + N1s8 + N28) {
        int i2 = idx8 - N1n8 - N1s8;
        int lane = i2 & 63, f = i2 >> 6;
        int nt = f % NTILES, kt = f / NTILES;
        int k0 = kt * 32 + ((lane >> 4) << 3);
        int n = nt * 16 + (lane & 15);
        unsigned int o[4];
#pragma unroll
        for (int jp = 0; jp < 4; ++jp) {
            int ka = k0 + 2 * jp, kb = ka + 1;
            float v0 = (ka < 200 && n < 200) ? W2[(size_t)ka * 200 + n] : 0.f;
            float v1 = (kb < 200 && n < 200) ? W2[(size_t)kb * 200 + n] : 0.f;
            o[jp] = packh(v0, v1);
        }
        *(uint4*)&w2s[(size_t)i2 * 8] = make_uint4(o[0], o[1], o[2], o[3]);
    }
}

// ---------------------------------------------------------------------------
// K2: AB = emb(1024x768) @ [W1top|W1mid](768x448), fp16 MFMA, fp16 out.
//   256 one-wave blocks; register ping-pong prefetch.
// ---------------------------------------------------------------------------
__global__ __launch_bounds__(64)
void node_mfma(const unsigned short* __restrict__ emb,
               const unsigned short* __restrict__ w1n,
               unsigned short* __restrict__ AB) {
    int lane = threadIdx.x & 63;
    int q = lane >> 4, c = lane & 15;
    int mt = blockIdx.x >> 2;         // 0..63
    int ng = blockIdx.x & 3;          // 0..3
    int m0 = mt * 16;
    const uint4* ga = (const uint4*)emb + (size_t)(m0 + c) * 96;
    const uint4* gb = (const uint4*)w1n;

    f32x4 acc[7];
#pragma unroll
    for (int n = 0; n < 7; ++n) acc[n] = (f32x4){0.f, 0.f, 0.f, 0.f};

    uint4 aA, aB, bA[7], bB[7];
    aA = ga[q];
#pragma unroll
    for (int n = 0; n < 7; ++n) bA[n] = gb[((0 * 28 + ng * 7 + n) << 6) + lane];

#pragma unroll 1
    for (int kt = 0; kt < KT1; kt += 2) {
        aB = ga[(kt + 1) * 4 + q];
#pragma unroll
        for (int n = 0; n < 7; ++n) bB[n] = gb[(((kt + 1) * 28 + ng * 7 + n) << 6) + lane];
        {
            FragU a; a.u = aA;
#pragma unroll
            for (int n = 0; n < 7; ++n) {
                FragU bb; bb.u = bA[n];
                acc[n] = __builtin_amdgcn_mfma_f32_16x16x32_f16(a.h, bb.h, acc[n], 0, 0, 0);
            }
        }
        if (kt + 2 < KT1) {
            aA = ga[(kt + 2) * 4 + q];
#pragma unroll
            for (int n = 0; n < 7; ++n) bA[n] = gb[(((kt + 2) * 28 + ng * 7 + n) << 6) + lane];
        }
        {
            FragU a; a.u = aB;
#pragma unroll
            for (int n = 0; n < 7; ++n) {
                FragU bb; bb.u = bB[n];
                acc[n] = __builtin_amdgcn_mfma_f32_16x16x32_f16(a.h, bb.h, acc[n], 0, 0, 0);
            }
        }
    }
#pragma unroll
    for (int n = 0; n < 7; ++n) {
        int col = (ng * 7 + n) * 16 + c;
#pragma unroll
        for (int rr = 0; rr < 4; ++rr)
            AB[(size_t)(m0 + q * 4 + rr) * ABS + col] = f2h(acc[n][rr]);
    }
}

// ---------------------------------------------------------------------------
// K3: pair MLP (R17 geometry) + fused masked softmax.
//   Block = 128 threads = 2 waves for one (tile, 4-i-row group rp).
//   acc[4][7], ping-pong prefetch, setprio around MFMA bursts.
//   Tail: agent-scope S stores; last-writer-per-row does the softmax.
// ---------------------------------------------------------------------------
__global__ __launch_bounds__(128, 2)
void pair_wave(
    const unsigned short* __restrict__ emb,
    const unsigned short* __restrict__ w1s,
    const unsigned short* __restrict__ w2s,
    const unsigned short* __restrict__ AB,
    const float* __restrict__ b1, const float* __restrict__ b2,
    const float* __restrict__ W3, const float* __restrict__ b3,
    float* __restrict__ S, int* __restrict__ cnt, float* __restrict__ out) {
    int bid = blockIdx.x;
    int rp = bid / 544;               // 0..3 : 4-row group within tile
    int g = bid % 544;                // tile id; mates 544 apart (544%8==0)
    int b = g / TRI;
    int r = g % TRI;
    int ti = (int)((sqrtf(8.f * (float)r + 1.f) - 1.f) * 0.5f);
    while ((ti + 1) * (ti + 2) / 2 <= r) ++ti;
    while (ti * (ti + 1) / 2 > r) --ti;
    int tj = r - ti * (ti + 1) / 2;
    int i0 = ti << 4, j0 = tj << 4;

    int tid = threadIdx.x;
    int lane = tid & 63;
    int nh = tid >> 6;                // 0..1 (ntile half)
    int q = lane >> 4, c = lane & 15;
    int iA = i0 + rp * 4;             // rows iA..iA+3

    __shared__ __align__(16) unsigned short smH[4 * MTS];   // 28672 B (4 slots)
    __shared__ float sred[2][64];                           //   512 B
    __shared__ int rowsF[4];
    __shared__ int nfS;
    __shared__ float smax[2], ssum[2];

    const uint4* w1f = (const uint4*)w1s;
    const uint4* w2f = (const uint4*)w2s;
    const uint4* gI[4];
#pragma unroll
    for (int t = 0; t < 4; ++t)
        gI[t] = (const uint4*)(emb + ((size_t)b * NN + iA + t) * DD);
    const uint4* gJc = (const uint4*)(emb + ((size_t)b * NN + j0 + c) * DD);

    // ---- phase 1: acc[4][7] over K=768, ping-pong prefetch ----
    f32x4 acc[4][7];
#pragma unroll
    for (int t = 0; t < 4; ++t)
#pragma unroll
        for (int n = 0; n < 7; ++n)
            acc[t][n] = (f32x4){0.f, 0.f, 0.f, 0.f};

    {
        uint4 bfrA[7], bfrB[7];
        uint4 ejA, ejB, eA[4], eB[4];
#pragma unroll
        for (int n = 0; n < 7; ++n) bfrA[n] = w1f[(nh * 7 + n) * 64 + lane];
        ejA = gJc[q];
#pragma unroll
        for (int t = 0; t < 4; ++t) eA[t] = gI[t][q];

#pragma unroll 1
        for (int kt = 0; kt < KT1; kt += 2) {
            // prefetch kt+1 -> B
#pragma unroll
            for (int n = 0; n < 7; ++n)
                bfrB[n] = w1f[((kt + 1) * NTILES + nh * 7 + n) * 64 + lane];
            ejB = gJc[(kt + 1) * 4 + q];
#pragma unroll
            for (int t = 0; t < 4; ++t) eB[t] = gI[t][(kt + 1) * 4 + q];
            // compute kt (A)
            __builtin_amdgcn_s_setprio(1);
#pragma unroll
            for (int t = 0; t < 4; ++t) {
                FragU a;
                a.u.x = h2mul(eA[t].x, ejA.x); a.u.y = h2mul(eA[t].y, ejA.y);
                a.u.z = h2mul(eA[t].z, ejA.z); a.u.w = h2mul(eA[t].w, ejA.w);
#pragma unroll
                for (int n = 0; n < 7; ++n) {
                    FragU bb; bb.u = bfrA[n];
                    acc[t][n] = __builtin_amdgcn_mfma_f32_16x16x32_f16(a.h, bb.h, acc[t][n], 0, 0, 0);
                }
            }
            __builtin_amdgcn_s_setprio(0);
            // prefetch kt+2 -> A
            if (kt + 2 < KT1) {
#pragma unroll
                for (int n = 0; n < 7; ++n)
                    bfrA[n] = w1f[((kt + 2) * NTILES + nh * 7 + n) * 64 + lane];
                ejA = gJc[(kt + 2) * 4 + q];
#pragma unroll
                for (int t = 0; t < 4; ++t) eA[t] = gI[t][(kt + 2) * 4 + q];
            }
            // compute kt+1 (B)
            __builtin_amdgcn_s_setprio(1);
#pragma unroll
            for (int t = 0; t < 4; ++t) {
                FragU a;
                a.u.x = h2mul(eB[t].x, ejB.x); a.u.y = h2mul(eB[t].y, ejB.y);
                a.u.z = h2mul(eB[t].z, ejB.z); a.u.w = h2mul(eB[t].w, ejB.w);
#pragma unroll
                for (int n = 0; n < 7; ++n) {
                    FragU bb; bb.u = bfrB[n];
                    acc[t][n] = __builtin_amdgcn_mfma_f32_16x16x32_f16(a.h, bb.h, acc[t][n], 0, 0, 0);
                }
            }
            __builtin_amdgcn_s_setprio(0);
        }
    }

    // ---- epilogue: h1 = relu(acc + A[i] + Bv[j] + b1) -> smH (nh half) ----
    {
        unsigned int bvp[7][2];
#pragma unroll
        for (int n = 0; n < 7; ++n) {
            int h = ((nh * 7 + n) << 4) + c;
#pragma unroll
            for (int p = 0; p < 2; ++p) {
                unsigned int lo = AB[((size_t)b * NN + j0 + q * 4 + 2 * p) * ABS + HP + h];
                unsigned int hi = AB[((size_t)b * NN + j0 + q * 4 + 2 * p + 1) * ABS + HP + h];
                bvp[n][p] = (hi << 16) | lo;
            }
        }
#pragma unroll
        for (int t = 0; t < 4; ++t) {
            unsigned short* slot = &smH[t * MTS];
#pragma unroll
            for (int n = 0; n < 7; ++n) {
                int h = ((nh * 7 + n) << 4) + c;
                float b1v = (h < 200) ? b1[h] : 0.f;
                float af = h2f(AB[((size_t)b * NN + iA + t) * ABS + h]) + b1v;
                int kk2 = h >> 5, q2 = (h >> 3) & 3, j2 = h & 7;
                int fa = ((kk2 * 4 + q2) << 7) + j2;        // + jj*8 below
#pragma unroll
                for (int rr = 0; rr < 4; ++rr) {
                    float bvf = (rr & 1) ? hhi(bvp[n][rr >> 1]) : hlo(bvp[n][rr >> 1]);
                    slot[fa + ((q * 4 + rr) << 3)] =
                        f2h(fmaxf(acc[t][n][rr] + af + bvf, 0.f));
                }
            }
        }
    }
    __syncthreads();   // B1: both h-halves of all 4 slots in smH

    // ---- phase 2: acc2[4][7] over K=224, ping-pong weight prefetch ----
    f32x4 acc2[4][7];
#pragma unroll
    for (int t = 0; t < 4; ++t)
#pragma unroll
        for (int n = 0; n < 7; ++n)
            acc2[t][n] = (f32x4){0.f, 0.f, 0.f, 0.f};

    {
        uint4 bfrA[7], bfrB[7];
#pragma unroll
        for (int n = 0; n < 7; ++n) bfrA[n] = w2f[(nh * 7 + n) * 64 + lane];

#pragma unroll 1
        for (int kk = 0; kk < 6; kk += 2) {
#pragma unroll
            for (int n = 0; n < 7; ++n)
                bfrB[n] = w2f[((kk + 1) * NTILES + nh * 7 + n) * 64 + lane];
            __builtin_amdgcn_s_setprio(1);
#pragma unroll
            for (int t = 0; t < 4; ++t) {
                FragU a2;
                a2.u = *(const uint4*)(&smH[t * MTS + (((kk * 4 + q) * 16 + c) << 3)]);
#pragma unroll
                for (int n = 0; n < 7; ++n) {
                    FragU bb; bb.u = bfrA[n];
                    acc2[t][n] = __builtin_amdgcn_mfma_f32_16x16x32_f16(a2.h, bb.h, acc2[t][n], 0, 0, 0);
                }
            }
            __builtin_amdgcn_s_setprio(0);
#pragma unroll
            for (int n = 0; n < 7; ++n)
                bfrA[n] = w2f[((kk + 2) * NTILES + nh * 7 + n) * 64 + lane];
            __builtin_amdgcn_s_setprio(1);
#pragma unroll
            for (int t = 0; t < 4; ++t) {
                FragU a2;
                a2.u = *(const uint4*)(&smH[t * MTS + ((((kk + 1) * 4 + q) * 16 + c) << 3)]);
#pragma unroll
                for (int n = 0; n < 7; ++n) {
                    FragU bb; bb.u = bfrB[n];
                    acc2[t][n] = __builtin_amdgcn_mfma_f32_16x16x32_f16(a2.h, bb.h, acc2[t][n], 0, 0, 0);
                }
            }
            __builtin_amdgcn_s_setprio(0);
        }
        // tail kk=6 (already in bfrA)
        __builtin_amdgcn_s_setprio(1);
#pragma unroll
        for (int t = 0; t < 4; ++t) {
            FragU a2;
            a2.u = *(const uint4*)(&smH[t * MTS + (((6 * 4 + q) * 16 + c) << 3)]);
#pragma unroll
            for (int n = 0; n < 7; ++n) {
                FragU bb; bb.u = bfrA[n];
                acc2[t][n] = __builtin_amdgcn_mfma_f32_16x16x32_f16(a2.h, bb.h, acc2[t][n], 0, 0, 0);
            }
        }
        __builtin_amdgcn_s_setprio(0);
    }

    // ---- phase 3: partial dot relu(h2+b2).W3 over nh half -> sred ----
    {
        float b2v[7], w3v[7];
#pragma unroll
        for (int n = 0; n < 7; ++n) {
            int h = ((nh * 7 + n) << 4) + c;
            b2v[n] = (h < 200) ? b2[h] : 0.f;
            w3v[n] = (h < 200) ? W3[h] : 0.f;
        }
#pragma unroll
        for (int t = 0; t < 4; ++t) {
#pragma unroll
            for (int rr = 0; rr < 4; ++rr) {
                float part = 0.f;
#pragma unroll
                for (int n = 0; n < 7; ++n) {
                    float hv = fmaxf(acc2[t][n][rr] + b2v[n], 0.f);
                    part += hv * w3v[n];
                }
                part += __shfl_xor(part, 1);
                part += __shfl_xor(part, 2);
                part += __shfl_xor(part, 4);
                part += __shfl_xor(part, 8);
                if (c == 0)
                    sred[nh][t * 16 + q * 4 + rr] = part;
            }
        }
    }
    __syncthreads();   // B2: both partials in sred

    // ---- store this group's 64 pairs (agent-visible) ----
    if (tid < 64) {
        int t = tid >> 4, jj = tid & 15;
        float s = sred[0][tid] + sred[1][tid] + b3[0];
        __hip_atomic_store(&S[((size_t)b * NN + iA + t) * NN + j0 + jj], s,
                           __ATOMIC_RELAXED, __HIP_MEMORY_SCOPE_AGENT);
    }
    if (tid == 0) nfS = 0;
    __syncthreads();   // B3: S stores drained (vmcnt) + nfS init

    // ---- last writer of each row performs its masked softmax ----
    if (tid < 4) {
        int i = iA + tid;
        int need = (i >> 4) + 1;          // writers = tiles tj=0..ti
        int old = __hip_atomic_fetch_add(&cnt[b * NN + i], 1,
                                         __ATOMIC_ACQ_REL, __HIP_MEMORY_SCOPE_AGENT);
        if (old + 1 == need) rowsF[atomicAdd(&nfS, 1)] = i;
    }
    __syncthreads();

    for (int f = 0; f < nfS; ++f) {
        int i = rowsF[f];
        const float* rowp = &S[((size_t)b * NN + i) * NN];
        int ja = tid, jb = tid + 128;
        float va = __hip_atomic_load(&rowp[ja], __ATOMIC_RELAXED, __HIP_MEMORY_SCOPE_AGENT);
        float vb = __hip_atomic_load(&rowp[jb], __ATOMIC_RELAXED, __HIP_MEMORY_SCOPE_AGENT);
        float xa = (ja < i) ? va : ((ja == i) ? 0.f : -1e30f);
        float xb = (jb < i) ? vb : ((jb == i) ? 0.f : -1e30f);
        float m = fmaxf(xa, xb);
#pragma unroll
        for (int off = 32; off; off >>= 1) m = fmaxf(m, __shfl_xor(m, off));
        if (lane == 0) smax[nh] = m;
        __syncthreads();
        float mx = fmaxf(smax[0], smax[1]);
        float ea = (ja <= i) ? __expf(xa - mx) : 0.f;
        float eb = (jb <= i) ? __expf(xb - mx) : 0.f;
        float s = ea + eb;
#pragma unroll
        for (int off = 32; off; off >>= 1) s += __shfl_xor(s, off);
        if (lane == 0) ssum[nh] = s;
        __syncthreads();
        float sum = ssum[0] + ssum[1];
        out[((size_t)b * NN + i) * NN + ja] = (ja <= i) ? (ea / sum) : -1000.0f;
        out[((size_t)b * NN + i) * NN + jb] = (jb <= i) ? (eb / sum) : -1000.0f;
        __syncthreads();   // smax/ssum reuse across f
    }
}

// ---------------------------------------------------------------------------
extern "C" void kernel_launch(void* const* d_in, const int* in_sizes, int n_in,
                              void* d_out, int out_size, void* d_ws, size_t ws_size,
                              hipStream_t stream) {
    const float* ee  = (const float*)d_in[0];
    const int*   eidx = (const int*)d_in[1];
    const float* W1  = (const float*)d_in[2];
    const float* b1  = (const float*)d_in[3];
    const float* W2  = (const float*)d_in[4];
    const float* b2  = (const float*)d_in[5];
    const float* W3  = (const float*)d_in[6];
    const float* b3  = (const float*)d_in[7];
    float* out = (float*)d_out;

    char* p = (char*)d_ws;
    unsigned short* emb = (unsigned short*)p; p += (size_t)NB * NN * DD * 2;       // 1.5 MB
    unsigned short* w1n = (unsigned short*)p; p += (size_t)24 * 28 * 512 * 2;      // 672 KB
    unsigned short* w1s = (unsigned short*)p; p += (size_t)24 * 14 * 512 * 2;      // 336 KB
    unsigned short* w2s = (unsigned short*)p; p += (size_t)7 * 14 * 512 * 2;       // 98 KB
    unsigned short* AB  = (unsigned short*)p; p += (size_t)NB * NN * ABS * 2;      // 896 KB
    float* S  = (float*)p; p += (size_t)NB * NN * NN * 4;                           // 1 MB
    int* cnt = (int*)p; p += (size_t)NB * NN * sizeof(int);                         // 4 KB

    hipMemsetAsync(cnt, 0, (size_t)NB * NN * sizeof(int), stream);
    prep_all<<<533, 256, 0, stream>>>(W1, W2, ee, eidx, w1n, w1s, w2s, emb);
    node_mfma<<<256, 64, 0, stream>>>(emb, w1n, AB);
    pair_wave<<<2176, 128, 0, stream>>>(emb, w1s, w2s, AB, b1, b2, W3, b3, S, cnt, out);
}

// Round 14
// 204.786 us; speedup vs baseline: 1.2047x; 1.1460x over previous
//
#include <hip/hip_runtime.h>

// ---------------------------------------------------------------------------
// CorefPairScorer: B=4, T=4096, D=768, N=256, HID=200 (padded to 224)
// h1(i,j) = relu(A[i] + Bv[j] + (emb_i*emb_j)@W1bot + b1)
// h2 = relu(h1@W2 + b2); s = h2@W3 + b3; masked softmax rows.
// FINAL (R20 = R17 restored): best verified config, 203.3us total.
//   pair_wave: 2-wave blocks, 4 i-rows/wave, acc[4][7], register ping-pong
//   prefetch, setprio(1) around MFMA bursts. Plateau evidence:
//   R13 (3w/SIMD, acc[2][7])        119us   - less ILP
//   R14 (+reg ping-pong)            119->110 (as R15)
//   R15 (4 rows/wave, 2w/SIMD)      110us   - density/occupancy optimum
//   R16 (8 rows/wave)               178us   - 256-VGPR spill + <1 w/SIMD
//   R17 (+setprio, vec prep)        106.7us - BEST
//   R18 (LDS-DMA weights, vmcnt)    148us   - extra LDS round-trip, low occ
//   R19 (fused softmax tail)        141us   - tail protocol cost >> 3.5us
//                                             saved by removing the kernel
//   Latency-bound equilibrium: 240 unified regs/wave caps 2 waves/SIMD;
//   MfmaUtil 24% / VALU 22% / HBM 1.4% - no saturated pipe, no free lever.
// ---------------------------------------------------------------------------

#define NB 4
#define NN 256
#define DD 768
#define TT 4096
#define HP 224
#define NTILES 14
#define KT1 24
#define KT2 7
#define TRI 136
#define ABS 448          // AB row stride (fp16): [A(224) | B(224)]
#define MTS 3584         // shorts per packed Mtile (16 rows x 224)

typedef _Float16 f16x8 __attribute__((ext_vector_type(8)));
typedef _Float16 f16x2 __attribute__((ext_vector_type(2)));
typedef __attribute__((ext_vector_type(4))) float f32x4;

union FragU { uint4 u; f16x8 h; };
union H2U { unsigned int u; f16x2 h; };

__device__ __forceinline__ unsigned int h2mul(unsigned int a, unsigned int b) {
    H2U x, y, r; x.u = a; y.u = b; r.h = x.h * y.h;   // v_pk_mul_f16
    return r.u;
}
__device__ __forceinline__ float hlo(unsigned int v) { H2U x; x.u = v; return (float)x.h[0]; }
__device__ __forceinline__ float hhi(unsigned int v) { H2U x; x.u = v; return (float)x.h[1]; }
__device__ __forceinline__ unsigned short f2h(float f) {
    _Float16 h = (_Float16)f;
    union { _Float16 h; unsigned short u; } r; r.h = h; return r.u;
}
__device__ __forceinline__ float h2f(unsigned short u) {
    union { unsigned short u; _Float16 h; } r; r.u = u; return (float)r.h;
}
__device__ __forceinline__ unsigned int packh(float lo, float hi) {  // RNE pair
    return ((unsigned int)f2h(hi) << 16) | (unsigned int)f2h(lo);
}

// ---------------------------------------------------------------------------
// K0 (merged, vectorized): weight swizzle blocks 0..276 (8 elems/thread,
// uint4 stores) + gather/cast blocks 277..532 (4 rows/block, packed stores).
//   frag layout: buf[((kt*NT+nt)*64+lane)*8+j] = W[kt*32+(lane>>4)*8+j][nt*16+(lane&15)]
// ---------------------------------------------------------------------------
__global__ void prep_all(const float* __restrict__ W1, const float* __restrict__ W2,
                         const float* __restrict__ ee, const int* __restrict__ eidx,
                         unsigned short* __restrict__ w1n,
                         unsigned short* __restrict__ w1s,
                         unsigned short* __restrict__ w2s,
                         unsigned short* __restrict__ emb) {
    const int N1n8 = 24 * 28 * 64;   // 43008  (uint4-granular counts)
    const int N1s8 = 24 * 14 * 64;   // 21504
    const int N28  = 7 * 14 * 64;    // 6272
    int bx = blockIdx.x;
    if (bx >= 277) {                  // gather + fp32->fp16, 4 rows/block
        int tid = threadIdx.x;
        int m = (bx - 277) * 4 + (tid >> 6);   // global row 0..1023
        int lane = tid & 63;
        int b = m >> 8, n = m & 255;
        int t = eidx[b * NN + n];
        const float* src = ee + ((size_t)b * TT + t) * DD;
        uint4* dst = (uint4*)(emb + ((size_t)b * NN + n) * DD);
        for (int chunk = lane; chunk < 96; chunk += 64) {
            const float4* s4 = (const float4*)(src + chunk * 8);
            float4 lo4 = s4[0], hi4 = s4[1];
            uint4 o;
            o.x = packh(lo4.x, lo4.y); o.y = packh(lo4.z, lo4.w);
            o.z = packh(hi4.x, hi4.y); o.w = packh(hi4.z, hi4.w);
            dst[chunk] = o;
        }
        return;
    }
    int idx8 = bx * 256 + threadIdx.x;
    if (idx8 < N1n8) {
        int lane = idx8 & 63, f = idx8 >> 6;
        int nt = f % 28, kt = f / 28;
        int k0 = kt * 32 + ((lane >> 4) << 3);     // base k, +j below
        int n = nt * 16 + (lane & 15);             // 0..447
        unsigned int o[4];
#pragma unroll
        for (int jp = 0; jp < 4; ++jp) {
            float v0, v1;
            int ka = k0 + 2 * jp, kb = ka + 1;
            if (n < HP) {
                v0 = (n < 200) ? W1[(size_t)ka * 200 + n] : 0.f;
                v1 = (n < 200) ? W1[(size_t)kb * 200 + n] : 0.f;
            } else {
                int c2 = n - HP;
                v0 = (c2 < 200) ? W1[(size_t)(768 + ka) * 200 + c2] : 0.f;
                v1 = (c2 < 200) ? W1[(size_t)(768 + kb) * 200 + c2] : 0.f;
            }
            o[jp] = packh(v0, v1);
        }
        *(uint4*)&w1n[(size_t)idx8 * 8] = make_uint4(o[0], o[1], o[2], o[3]);
    } else if (idx8 < N1n8 + N1s8) {
        int i2 = idx8 - N1n8;
        int lane = i2 & 63, f = i2 >> 6;
        int nt = f % NTILES, kt = f / NTILES;
        int k0 = kt * 32 + ((lane >> 4) << 3);
        int n = nt * 16 + (lane & 15);
        unsigned int o[4];
#pragma unroll
        for (int jp = 0; jp < 4; ++jp) {
            int ka = k0 + 2 * jp, kb = ka + 1;
            float v0 = (n < 200) ? W1[(size_t)(1536 + ka) * 200 + n] : 0.f;
            float v1 = (n < 200) ? W1[(size_t)(1536 + kb) * 200 + n] : 0.f;
            o[jp] = packh(v0, v1);
        }
        *(uint4*)&w1s[(size_t)i2 * 8] = make_uint4(o[0], o[1], o[2], o[3]);
    } else if (idx8 < N1n8 + N1s8 + N28) {
        int i2 = idx8 - N1n8 - N1s8;
        int lane = i2 & 63, f = i2 >> 6;
        int nt = f % NTILES, kt = f / NTILES;
        int k0 = kt * 32 + ((lane >> 4) << 3);
        int n = nt * 16 + (lane & 15);
        unsigned int o[4];
#pragma unroll
        for (int jp = 0; jp < 4; ++jp) {
            int ka = k0 + 2 * jp, kb = ka + 1;
            float v0 = (ka < 200 && n < 200) ? W2[(size_t)ka * 200 + n] : 0.f;
            float v1 = (kb < 200 && n < 200) ? W2[(size_t)kb * 200 + n] : 0.f;
            o[jp] = packh(v0, v1);
        }
        *(uint4*)&w2s[(size_t)i2 * 8] = make_uint4(o[0], o[1], o[2], o[3]);
    }
}

// ---------------------------------------------------------------------------
// K2: AB = emb(1024x768) @ [W1top|W1mid](768x448), fp16 MFMA, fp16 out.
//   256 one-wave blocks; register ping-pong prefetch.
// ---------------------------------------------------------------------------
__global__ __launch_bounds__(64)
void node_mfma(const unsigned short* __restrict__ emb,
               const unsigned short* __restrict__ w1n,
               unsigned short* __restrict__ AB) {
    int lane = threadIdx.x & 63;
    int q = lane >> 4, c = lane & 15;
    int mt = blockIdx.x >> 2;         // 0..63
    int ng = blockIdx.x & 3;          // 0..3
    int m0 = mt * 16;
    const uint4* ga = (const uint4*)emb + (size_t)(m0 + c) * 96;
    const uint4* gb = (const uint4*)w1n;

    f32x4 acc[7];
#pragma unroll
    for (int n = 0; n < 7; ++n) acc[n] = (f32x4){0.f, 0.f, 0.f, 0.f};

    uint4 aA, aB, bA[7], bB[7];
    aA = ga[q];
#pragma unroll
    for (int n = 0; n < 7; ++n) bA[n] = gb[((0 * 28 + ng * 7 + n) << 6) + lane];

#pragma unroll 1
    for (int kt = 0; kt < KT1; kt += 2) {
        aB = ga[(kt + 1) * 4 + q];
#pragma unroll
        for (int n = 0; n < 7; ++n) bB[n] = gb[(((kt + 1) * 28 + ng * 7 + n) << 6) + lane];
        {
            FragU a; a.u = aA;
#pragma unroll
            for (int n = 0; n < 7; ++n) {
                FragU bb; bb.u = bA[n];
                acc[n] = __builtin_amdgcn_mfma_f32_16x16x32_f16(a.h, bb.h, acc[n], 0, 0, 0);
            }
        }
        if (kt + 2 < KT1) {
            aA = ga[(kt + 2) * 4 + q];
#pragma unroll
            for (int n = 0; n < 7; ++n) bA[n] = gb[(((kt + 2) * 28 + ng * 7 + n) << 6) + lane];
        }
        {
            FragU a; a.u = aB;
#pragma unroll
            for (int n = 0; n < 7; ++n) {
                FragU bb; bb.u = bB[n];
                acc[n] = __builtin_amdgcn_mfma_f32_16x16x32_f16(a.h, bb.h, acc[n], 0, 0, 0);
            }
        }
    }
#pragma unroll
    for (int n = 0; n < 7; ++n) {
        int col = (ng * 7 + n) * 16 + c;
#pragma unroll
        for (int rr = 0; rr < 4; ++rr)
            AB[(size_t)(m0 + q * 4 + rr) * ABS + col] = f2h(acc[n][rr]);
    }
}

// ---------------------------------------------------------------------------
// K3: pair MLP (R15 geometry). Block = 128 threads = 2 waves (the nh pair)
//   for one (tile, 4-i-row group rp). acc[4][7] (28 MFMA per 7 weight loads),
//   ping-pong prefetch, setprio(1) around MFMA bursts (independent waves).
// ---------------------------------------------------------------------------
__global__ __launch_bounds__(128, 2)
void pair_wave(
    const unsigned short* __restrict__ emb,
    const unsigned short* __restrict__ w1s,
    const unsigned short* __restrict__ w2s,
    const unsigned short* __restrict__ AB,
    const float* __restrict__ b1, const float* __restrict__ b2,
    const float* __restrict__ W3, const float* __restrict__ b3,
    float* __restrict__ S) {
    int bid = blockIdx.x;
    int rp = bid / 544;               // 0..3 : 4-row group within tile
    int g = bid % 544;                // tile id; mates 544 apart (544%8==0)
    int b = g / TRI;
    int r = g % TRI;
    int ti = (int)((sqrtf(8.f * (float)r + 1.f) - 1.f) * 0.5f);
    while ((ti + 1) * (ti + 2) / 2 <= r) ++ti;
    while (ti * (ti + 1) / 2 > r) --ti;
    int tj = r - ti * (ti + 1) / 2;
    int i0 = ti << 4, j0 = tj << 4;

    int tid = threadIdx.x;
    int lane = tid & 63;
    int nh = tid >> 6;                // 0..1 (ntile half)
    int q = lane >> 4, c = lane & 15;
    int iA = i0 + rp * 4;             // rows iA..iA+3

    __shared__ __align__(16) unsigned short smH[4 * MTS];   // 28672 B (4 slots)
    __shared__ float sred[2][64];                           //   512 B

    const uint4* w1f = (const uint4*)w1s;
    const uint4* w2f = (const uint4*)w2s;
    const uint4* gI[4];
#pragma unroll
    for (int t = 0; t < 4; ++t)
        gI[t] = (const uint4*)(emb + ((size_t)b * NN + iA + t) * DD);
    const uint4* gJc = (const uint4*)(emb + ((size_t)b * NN + j0 + c) * DD);

    // ---- phase 1: acc[4][7] over K=768, ping-pong prefetch ----
    f32x4 acc[4][7];
#pragma unroll
    for (int t = 0; t < 4; ++t)
#pragma unroll
        for (int n = 0; n < 7; ++n)
            acc[t][n] = (f32x4){0.f, 0.f, 0.f, 0.f};

    {
        uint4 bfrA[7], bfrB[7];
        uint4 ejA, ejB, eA[4], eB[4];
#pragma unroll
        for (int n = 0; n < 7; ++n) bfrA[n] = w1f[(nh * 7 + n) * 64 + lane];
        ejA = gJc[q];
#pragma unroll
        for (int t = 0; t < 4; ++t) eA[t] = gI[t][q];

#pragma unroll 1
        for (int kt = 0; kt < KT1; kt += 2) {
            // prefetch kt+1 -> B
#pragma unroll
            for (int n = 0; n < 7; ++n)
                bfrB[n] = w1f[((kt + 1) * NTILES + nh * 7 + n) * 64 + lane];
            ejB = gJc[(kt + 1) * 4 + q];
#pragma unroll
            for (int t = 0; t < 4; ++t) eB[t] = gI[t][(kt + 1) * 4 + q];
            // compute kt (A)
            __builtin_amdgcn_s_setprio(1);
#pragma unroll
            for (int t = 0; t < 4; ++t) {
                FragU a;
                a.u.x = h2mul(eA[t].x, ejA.x); a.u.y = h2mul(eA[t].y, ejA.y);
                a.u.z = h2mul(eA[t].z, ejA.z); a.u.w = h2mul(eA[t].w, ejA.w);
#pragma unroll
                for (int n = 0; n < 7; ++n) {
                    FragU bb; bb.u = bfrA[n];
                    acc[t][n] = __builtin_amdgcn_mfma_f32_16x16x32_f16(a.h, bb.h, acc[t][n], 0, 0, 0);
                }
            }
            __builtin_amdgcn_s_setprio(0);
            // prefetch kt+2 -> A
            if (kt + 2 < KT1) {
#pragma unroll
                for (int n = 0; n < 7; ++n)
                    bfrA[n] = w1f[((kt + 2) * NTILES + nh * 7 + n) * 64 + lane];
                ejA = gJc[(kt + 2) * 4 + q];
#pragma unroll
                for (int t = 0; t < 4; ++t) eA[t] = gI[t][(kt + 2) * 4 + q];
            }
            // compute kt+1 (B)
            __builtin_amdgcn_s_setprio(1);
#pragma unroll
            for (int t = 0; t < 4; ++t) {
                FragU a;
                a.u.x = h2mul(eB[t].x, ejB.x); a.u.y = h2mul(eB[t].y, ejB.y);
                a.u.z = h2mul(eB[t].z, ejB.z); a.u.w = h2mul(eB[t].w, ejB.w);
#pragma unroll
                for (int n = 0; n < 7; ++n) {
                    FragU bb; bb.u = bfrB[n];
                    acc[t][n] = __builtin_amdgcn_mfma_f32_16x16x32_f16(a.h, bb.h, acc[t][n], 0, 0, 0);
                }
            }
            __builtin_amdgcn_s_setprio(0);
        }
    }

    // ---- epilogue: h1 = relu(acc + A[i] + Bv[j] + b1) -> smH (nh half) ----
    {
        unsigned int bvp[7][2];
#pragma unroll
        for (int n = 0; n < 7; ++n) {
            int h = ((nh * 7 + n) << 4) + c;
#pragma unroll
            for (int p = 0; p < 2; ++p) {
                unsigned int lo = AB[((size_t)b * NN + j0 + q * 4 + 2 * p) * ABS + HP + h];
                unsigned int hi = AB[((size_t)b * NN + j0 + q * 4 + 2 * p + 1) * ABS + HP + h];
                bvp[n][p] = (hi << 16) | lo;
            }
        }
#pragma unroll
        for (int t = 0; t < 4; ++t) {
            unsigned short* slot = &smH[t * MTS];
#pragma unroll
            for (int n = 0; n < 7; ++n) {
                int h = ((nh * 7 + n) << 4) + c;
                float b1v = (h < 200) ? b1[h] : 0.f;
                float af = h2f(AB[((size_t)b * NN + iA + t) * ABS + h]) + b1v;
                int kk2 = h >> 5, q2 = (h >> 3) & 3, j2 = h & 7;
                int fa = ((kk2 * 4 + q2) << 7) + j2;        // + jj*8 below
#pragma unroll
                for (int rr = 0; rr < 4; ++rr) {
                    float bvf = (rr & 1) ? hhi(bvp[n][rr >> 1]) : hlo(bvp[n][rr >> 1]);
                    slot[fa + ((q * 4 + rr) << 3)] =
                        f2h(fmaxf(acc[t][n][rr] + af + bvf, 0.f));
                }
            }
        }
    }
    __syncthreads();   // B1: both h-halves of all 4 slots in smH

    // ---- phase 2: acc2[4][7] over K=224, ping-pong weight prefetch ----
    f32x4 acc2[4][7];
#pragma unroll
    for (int t = 0; t < 4; ++t)
#pragma unroll
        for (int n = 0; n < 7; ++n)
            acc2[t][n] = (f32x4){0.f, 0.f, 0.f, 0.f};

    {
        uint4 bfrA[7], bfrB[7];
#pragma unroll
        for (int n = 0; n < 7; ++n) bfrA[n] = w2f[(nh * 7 + n) * 64 + lane];

#pragma unroll 1
        for (int kk = 0; kk < 6; kk += 2) {
#pragma unroll
            for (int n = 0; n < 7; ++n)
                bfrB[n] = w2f[((kk + 1) * NTILES + nh * 7 + n) * 64 + lane];
            __builtin_amdgcn_s_setprio(1);
#pragma unroll
            for (int t = 0; t < 4; ++t) {
                FragU a2;
                a2.u = *(const uint4*)(&smH[t * MTS + (((kk * 4 + q) * 16 + c) << 3)]);
#pragma unroll
                for (int n = 0; n < 7; ++n) {
                    FragU bb; bb.u = bfrA[n];
                    acc2[t][n] = __builtin_amdgcn_mfma_f32_16x16x32_f16(a2.h, bb.h, acc2[t][n], 0, 0, 0);
                }
            }
            __builtin_amdgcn_s_setprio(0);
#pragma unroll
            for (int n = 0; n < 7; ++n)
                bfrA[n] = w2f[((kk + 2) * NTILES + nh * 7 + n) * 64 + lane];
            __builtin_amdgcn_s_setprio(1);
#pragma unroll
            for (int t = 0; t < 4; ++t) {
                FragU a2;
                a2.u = *(const uint4*)(&smH[t * MTS + ((((kk + 1) * 4 + q) * 16 + c) << 3)]);
#pragma unroll
                for (int n = 0; n < 7; ++n) {
                    FragU bb; bb.u = bfrB[n];
                    acc2[t][n] = __builtin_amdgcn_mfma_f32_16x16x32_f16(a2.h, bb.h, acc2[t][n], 0, 0, 0);
                }
            }
            __builtin_amdgcn_s_setprio(0);
        }
        // tail kk=6 (already in bfrA)
        __builtin_amdgcn_s_setprio(1);
#pragma unroll
        for (int t = 0; t < 4; ++t) {
            FragU a2;
            a2.u = *(const uint4*)(&smH[t * MTS + (((6 * 4 + q) * 16 + c) << 3)]);
#pragma unroll
            for (int n = 0; n < 7; ++n) {
                FragU bb; bb.u = bfrA[n];
                acc2[t][n] = __builtin_amdgcn_mfma_f32_16x16x32_f16(a2.h, bb.h, acc2[t][n], 0, 0, 0);
            }
        }
        __builtin_amdgcn_s_setprio(0);
    }

    // ---- phase 3: partial dot relu(h2+b2).W3 over nh half -> sred ----
    {
        float b2v[7], w3v[7];
#pragma unroll
        for (int n = 0; n < 7; ++n) {
            int h = ((nh * 7 + n) << 4) + c;
            b2v[n] = (h < 200) ? b2[h] : 0.f;
            w3v[n] = (h < 200) ? W3[h] : 0.f;
        }
#pragma unroll
        for (int t = 0; t < 4; ++t) {
#pragma unroll
            for (int rr = 0; rr < 4; ++rr) {
                float part = 0.f;
#pragma unroll
                for (int n = 0; n < 7; ++n) {
                    float hv = fmaxf(acc2[t][n][rr] + b2v[n], 0.f);
                    part += hv * w3v[n];
                }
                part += __shfl_xor(part, 1);
                part += __shfl_xor(part, 2);
                part += __shfl_xor(part, 4);
                part += __shfl_xor(part, 8);
                if (c == 0)
                    sred[nh][t * 16 + q * 4 + rr] = part;
            }
        }
    }
    __syncthreads();   // B2: both partials in sred

    if (tid < 64) {
        int t = tid >> 4, jj = tid & 15;
        float s = sred[0][tid] + sred[1][tid] + b3[0];
        S[((size_t)b * NN + iA + t) * NN + j0 + jj] = s;
    }
}

// ---------------------------------------------------------------------------
// K4: masked softmax per row; diag logit = 0; invalid -> -1000
// ---------------------------------------------------------------------------
__global__ __launch_bounds__(256) void softmax_rows(const float* __restrict__ S,
                                                    float* __restrict__ out) {
    int b = blockIdx.x >> 8, i = blockIdx.x & 255;
    int j = threadIdx.x;
    int lane = j & 63, w = j >> 6;
    __shared__ float red[16];
    float x = (j < i) ? S[((size_t)b * NN + i) * NN + j] : ((j == i) ? 0.f : -1e30f);
    float m = x;
#pragma unroll
    for (int off = 32; off; off >>= 1) m = fmaxf(m, __shfl_xor(m, off));
    if (lane == 0) red[w] = m;
    __syncthreads();
    float mx = fmaxf(fmaxf(red[0], red[1]), fmaxf(red[2], red[3]));
    float e = (j <= i) ? __expf(x - mx) : 0.f;
    float s = e;
#pragma unroll
    for (int off = 32; off; off >>= 1) s += __shfl_xor(s, off);
    if (lane == 0) red[8 + w] = s;
    __syncthreads();
    float sum = red[8] + red[9] + red[10] + red[11];
    out[((size_t)b * NN + i) * NN + j] = (j <= i) ? (e / sum) : -1000.0f;
}

// ---------------------------------------------------------------------------
extern "C" void kernel_launch(void* const* d_in, const int* in_sizes, int n_in,
                              void* d_out, int out_size, void* d_ws, size_t ws_size,
                              hipStream_t stream) {
    const float* ee  = (const float*)d_in[0];
    const int*   eidx = (const int*)d_in[1];
    const float* W1  = (const float*)d_in[2];
    const float* b1  = (const float*)d_in[3];
    const float* W2  = (const float*)d_in[4];
    const float* b2  = (const float*)d_in[5];
    const float* W3  = (const float*)d_in[6];
    const float* b3  = (const float*)d_in[7];
    float* out = (float*)d_out;

    char* p = (char*)d_ws;
    unsigned short* emb = (unsigned short*)p; p += (size_t)NB * NN * DD * 2;       // 1.5 MB
    unsigned short* w1n = (unsigned short*)p; p += (size_t)24 * 28 * 512 * 2;      // 672 KB
    unsigned short* w1s = (unsigned short*)p; p += (size_t)24 * 14 * 512 * 2;      // 336 KB
    unsigned short* w2s = (unsigned short*)p; p += (size_t)7 * 14 * 512 * 2;       // 98 KB
    unsigned short* AB  = (unsigned short*)p; p += (size_t)NB * NN * ABS * 2;      // 896 KB
    float* S  = (float*)p; p += (size_t)NB * NN * NN * 4;                           // 1 MB

    prep_all<<<533, 256, 0, stream>>>(W1, W2, ee, eidx, w1n, w1s, w2s, emb);
    node_mfma<<<256, 64, 0, stream>>>(emb, w1n, AB);
    pair_wave<<<2176, 128, 0, stream>>>(emb, w1s, w2s, AB, b1, b2, W3, b3, S);
    softmax_rows<<<NB * NN, 256, 0, stream>>>(S, out);
}